// Round 1
// baseline (2086.606 us; speedup 1.0000x reference)
//
#include <hip/hip_runtime.h>

// Exact DTW distance, antidiagonal wavefront, single workgroup.
// N=4096, 1024 threads x 4 rows/thread. Diagonal state lives in registers;
// only each thread's top cell crosses to its neighbor via double-buffered LDS.

#define N    4096
#define TPB  1024
#define CPT  4            // cells (rows) per thread
#define BIG  1e30f

__global__ __launch_bounds__(TPB, 1)
void dtw_wavefront(const float* __restrict__ xg, const float* __restrict__ yg,
                   float* __restrict__ out) {
    __shared__ float ylds[N];          // 16 KB
    __shared__ float tops[2][TPB];     // 8 KB, double-buffered neighbor handoff

    const int t = threadIdx.x;

    // stage y once (coalesced)
    for (int idx = t; idx < N; idx += TPB) ylds[idx] = yg[idx];
    tops[0][t] = BIG;
    tops[1][t] = BIG;

    const int i0 = t * CPT;
    const float x0 = xg[i0 + 0];
    const float x1 = xg[i0 + 1];
    const float x2 = xg[i0 + 2];
    const float x3 = xg[i0 + 3];

    // D on diagonals k-1 (d1) and k-2 (d2) for this thread's 4 rows
    float d1_0 = BIG, d1_1 = BIG, d1_2 = BIG, d1_3 = BIG;
    float d2_0 = BIG, d2_1 = BIG, d2_2 = BIG, d2_3 = BIG;
    // sliding window of y: yw[q] = y[j0 - q]
    float yw0 = 0.f, yw1 = 0.f, yw2 = 0.f, yw3 = 0.f;
    // neighbor (row i0-1) values on diag k-1 (read fresh) and k-2 (retained)
    float nb2 = BIG;

    int j0 = -i0;   // column of this thread's q=0 cell on diagonal k (starts k=0)

    __syncthreads();

    for (int k = 0; k < 2 * N - 1; ++k) {
        __syncthreads();   // makes step k-1 writes visible; guards buffer reuse

        // active iff any of this thread's 4 cells lies on diagonal k
        if ((unsigned)j0 <= (unsigned)(N + CPT - 2)) {
            // neighbor's top cell on diag k-1 (published into buffer (k-1)&1)
            float nb1 = (t > 0) ? tops[(k + 1) & 1][t - 1] : BIG;

            // slide y window: new element is y[j0] (clamped; masked if invalid)
            int jy = (j0 < N) ? j0 : (N - 1);
            float yn = ylds[jy];
            yw3 = yw2; yw2 = yw1; yw1 = yw0; yw0 = yn;

            // m(q) = min(D[i][j-1], D[i-1][j], D[i-1][j-1])  -> v_min3_f32
            float m0 = fminf(d1_0, fminf(nb1, nb2));
            float m1 = fminf(d1_1, fminf(d1_0, d2_0));
            float m2 = fminf(d1_2, fminf(d1_1, d2_1));
            float m3 = fminf(d1_3, fminf(d1_2, d2_2));
            if (k == 0 && t == 0) m0 = 0.0f;   // D[0][0] = c[0][0]

            float c0 = fabsf(x0 - yw0);
            float c1 = fabsf(x1 - yw1);
            float c2 = fabsf(x2 - yw2);
            float c3 = fabsf(x3 - yw3);

            // valid iff 0 <= j(q) < N  (j(q) = j0 - q)
            float dn0 = ((unsigned)(j0 - 0) < (unsigned)N) ? (c0 + m0) : BIG;
            float dn1 = ((unsigned)(j0 - 1) < (unsigned)N) ? (c1 + m1) : BIG;
            float dn2 = ((unsigned)(j0 - 2) < (unsigned)N) ? (c2 + m2) : BIG;
            float dn3 = ((unsigned)(j0 - 3) < (unsigned)N) ? (c3 + m3) : BIG;

            // publish this thread's top cell for neighbor t+1
            tops[k & 1][t] = dn3;

            // rotate diagonals
            d2_0 = d1_0; d2_1 = d1_1; d2_2 = d1_2; d2_3 = d1_3;
            d1_0 = dn0;  d1_1 = dn1;  d1_2 = dn2;  d1_3 = dn3;
            nb2 = nb1;
        }
        j0++;
    }

    // D[N-1][N-1] was computed on the last diagonal by thread TPB-1, cell q=3
    if (t == TPB - 1) out[0] = d1_3;
}

extern "C" void kernel_launch(void* const* d_in, const int* in_sizes, int n_in,
                              void* d_out, int out_size, void* d_ws, size_t ws_size,
                              hipStream_t stream) {
    const float* src = (const float*)d_in[0];
    const float* tgt = (const float*)d_in[1];
    float* out = (float*)d_out;
    hipLaunchKernelGGL(dtw_wavefront, dim3(1), dim3(TPB), 0, stream, src, tgt, out);
}

// Round 2
// 670.475 us; speedup vs baseline: 3.1121x; 3.1121x over previous
//
#include <hip/hip_runtime.h>

// Exact DTW, block-pipelined DP ("tile wavefront").
// 256 threads; thread t owns rows [16t, 16t+16). Columns processed in chunks
// of 8. Tile (t, c) executes at step s = t + c: thread t-1 writes the bottom
// row of chunk c one step before thread t needs it -> one barrier per step
// (767 total) instead of one per antidiagonal (8191).

#define N     4096
#define TPB   256
#define R     16            // rows per thread
#define C     8             // columns per chunk
#define NCH   (N / C)       // 512 chunks
#define STEPS (TPB + NCH - 1)
#define BIG   1e30f

// One DP column within a tile: dst[r] = |x_r - y_j| + min3(dst[r-1], src[r], src[r-1])
// (up = value just computed in same column; left = src[r]; diag = src[r-1]).
#define COLUMN(jj, SRC, DST, DG)                                            \
    {                                                                       \
        const int j = j0 + (jj);                                            \
        const float yj = ylds[j + (j >> 5)];                                \
        DST[0] = fabsf(x[0] - yj) + fminf(nb[(jj)], fminf(SRC[0], (DG)));   \
        _Pragma("unroll")                                                   \
        for (int r = 1; r < R; ++r)                                         \
            DST[r] = fabsf(x[r] - yj) +                                     \
                     fminf(DST[r - 1], fminf(SRC[r], SRC[r - 1]));          \
        bot[wb][t][(jj)] = DST[R - 1];                                      \
    }

__global__ __launch_bounds__(TPB, 1)
void dtw_tile(const float* __restrict__ xg, const float* __restrict__ yg,
              float* __restrict__ out) {
    __shared__ float ylds[N + N / 32];      // pad 1 float per 32 -> conflict-free stride-8 reads
    __shared__ float bot[2][TPB][C + 1];    // stride 9 (coprime 32) -> conflict-free handoff

    const int t = threadIdx.x;

    // stage y (coalesced), with pad-every-32 swizzle
    for (int j = t; j < N; j += TPB) ylds[j + (j >> 5)] = yg[j];

    // this thread's x rows (fixed for the whole run)
    float x[R];
    const int i0 = t * R;
    #pragma unroll
    for (int r = 0; r < R; ++r) x[r] = xg[i0 + r];

    // column-carry: cpA[r] = D[i0+r][j-1] at the left edge of the current chunk
    float cpA[R], cpB[R];
    #pragma unroll
    for (int r = 0; r < R; ++r) cpA[r] = BIG;   // D[i][-1]

    // diagc = D[i0-1][c*C - 1]. For t==0,c==0 the reference forces m=0 at (0,0):
    // min3(BIG, BIG, 0) = 0 reproduces it exactly. For t==0,c>0 it naturally
    // becomes BIG again (nb[] is BIG for t==0).
    float diagc = (t == 0) ? 0.0f : BIG;

    __syncthreads();

    for (int s = 0; s < STEPS; ++s) {
        __syncthreads();   // publishes step s-1 bottom rows; frees buffer s&1
        const int c = s - t;
        if (0 <= c && c < NCH) {
            const int rb = (s + 1) & 1;   // buffer written by neighbor at step s-1
            const int wb = s & 1;
            float nb[C];
            if (t > 0) {
                #pragma unroll
                for (int jj = 0; jj < C; ++jj) nb[jj] = bot[rb][t - 1][jj];
            } else {
                #pragma unroll
                for (int jj = 0; jj < C; ++jj) nb[jj] = BIG;
            }
            const int j0 = c * C;

            COLUMN(0, cpA, cpB, diagc)
            COLUMN(1, cpB, cpA, nb[0])
            COLUMN(2, cpA, cpB, nb[1])
            COLUMN(3, cpB, cpA, nb[2])
            COLUMN(4, cpA, cpB, nb[3])
            COLUMN(5, cpB, cpA, nb[4])
            COLUMN(6, cpA, cpB, nb[5])
            COLUMN(7, cpB, cpA, nb[6])
            // even column count: current state back in cpA

            diagc = nb[C - 1];
        }
    }

    // D[N-1][N-1]: thread TPB-1, row R-1, after its last chunk
    if (t == TPB - 1) out[0] = cpA[R - 1];
}

extern "C" void kernel_launch(void* const* d_in, const int* in_sizes, int n_in,
                              void* d_out, int out_size, void* d_ws, size_t ws_size,
                              hipStream_t stream) {
    const float* src = (const float*)d_in[0];
    const float* tgt = (const float*)d_in[1];
    float* out = (float*)d_out;
    hipLaunchKernelGGL(dtw_tile, dim3(1), dim3(TPB), 0, stream, src, tgt, out);
}